// Round 4
// baseline (225.313 us; speedup 1.0000x reference)
//
#include <hip/hip_runtime.h>
#include <hip/hip_bf16.h>

// RestrictedNN DAG. Round 4: MFMA for h1/h2 (round-3 design, compile fix:
// f2bf2 built from manual RNE rounding, no __hip_bfloat162 bit_cast).
// B=4096, L0=512 leaf modules (G=8,H=16), L1=64, L2=8 (FAN=8), root 128->16.
//
// k_prep: W1 [64][128][16] f32 -> W1t bf16 [64][16][128] (B-fragment layout),
//         W2 [8][128][16]  f32 -> W2t bf16 [8][16][128]. Runs every call.
// k_tree: 2048 blocks x 256. TB=16 rows x subtree s (s=blockIdx&7 == XCD).
//   stage x->bf16 LDS; phase A (VALU) gene+h0 -> LDS bf16;
//   phase B h1 = 8 x [16,128]x[128,16] MFMA; phase C h2 MFMA; h2->ws.
// k_root: root 128->16 + final dot(16).

#define TB 16
#define XSS 516      // ushorts per x row (512+4; 258 dw == 2 mod 32)
#define H0S 1032     // ushorts per h0 row (1024+8; 516 dw == 4 mod 32, 16B-aligned rows)
#define H1S 136      // ushorts per h1 row (128+8; 16B-aligned rows)

typedef __attribute__((ext_vector_type(8))) short short8;
typedef __attribute__((ext_vector_type(4))) float floatx4;

__device__ __forceinline__ float sigf(float v) {
    return __builtin_amdgcn_rcpf(1.0f + __expf(-v));
}
__device__ __forceinline__ float bflo(unsigned int p) {
    return __builtin_bit_cast(float, p << 16);
}
__device__ __forceinline__ float bfhi(unsigned int p) {
    return __builtin_bit_cast(float, p & 0xffff0000u);
}
__device__ __forceinline__ unsigned int f2bf_u32(float f) {   // RNE, returns bf16 in low 16
    unsigned int u = __builtin_bit_cast(unsigned int, f);
    return (u + 0x7fffu + ((u >> 16) & 1u)) >> 16;
}
__device__ __forceinline__ unsigned short f2bf(float f) {
    return (unsigned short)f2bf_u32(f);
}
__device__ __forceinline__ unsigned int f2bf2(float lo, float hi) {
    return f2bf_u32(lo) | (f2bf_u32(hi) << 16);
}

// ---- prep: transpose W1/W2 per module to bf16 [h][k] fragment layout ----
__global__ __launch_bounds__(256) void k_prep(
    const float* __restrict__ W1, const float* __restrict__ W2,
    unsigned short* __restrict__ W1t, unsigned short* __restrict__ W2t)
{
    __shared__ float wl[128 * 17];
    const int mb = blockIdx.x;              // 0..63 -> W1, 64..71 -> W2
    const float* src = (mb < 64) ? (W1 + (size_t)mb * 2048)
                                 : (W2 + (size_t)(mb - 64) * 2048);
    unsigned short* dst = (mb < 64) ? (W1t + (size_t)mb * 2048)
                                    : (W2t + (size_t)(mb - 64) * 2048);
    const int tid = threadIdx.x;
#pragma unroll
    for (int i = 0; i < 8; ++i) {
        const int idx = tid + i * 256;      // [k][h] in, coalesced
        wl[(idx >> 4) * 17 + (idx & 15)] = src[idx];
    }
    __syncthreads();
#pragma unroll
    for (int i = 0; i < 4; ++i) {
        const int u  = tid + i * 256;       // uint index over [h][k] bf16 out
        const int h  = u >> 6;
        const int k  = (u & 63) * 2;
        ((unsigned int*)dst)[u] = f2bf2(wl[k * 17 + h], wl[(k + 1) * 17 + h]);
    }
}

__global__ __launch_bounds__(256) void k_tree(
    const float* __restrict__ x, const float* __restrict__ Wg,
    const float* __restrict__ bg, const float* __restrict__ W0,
    const unsigned short* __restrict__ W1t, const unsigned short* __restrict__ W2t,
    float* __restrict__ h2ws)
{
    __shared__ __align__(16) unsigned short xs[TB * XSS];    // 16512 B (h1 reuses)
    __shared__ __align__(16) unsigned short h0s[TB * H0S];   // 33024 B
    unsigned short* h1u = xs;   // h1 [b][j*16+h] bf16, stride H1S; xs dead after A

    const int tid = threadIdx.x;
    const int s   = blockIdx.x & 7;
    const int b0  = (blockIdx.x >> 3) * TB;

    // ---------- stage x (coalesced f32 -> bf16 LDS) ----------
    {
        const float* xbase = x + (size_t)b0 * 4096 + s * 512;
#pragma unroll
        for (int t = 0; t < 8; ++t) {
            const int i = tid + t * 256;           // over TB*128 float4s
            const int r = i >> 7, c4 = i & 127;
            const float4 v = *(const float4*)(xbase + (size_t)r * 4096 + c4 * 4);
            *(uint2*)&xs[r * XSS + c4 * 4] = make_uint2(f2bf2(v.x, v.y), f2bf2(v.z, v.w));
        }
    }
    __syncthreads();

    // ---------- phase A: gene + h0 (VALU). lane-major over modules ----------
    {
        const int mg = tid & 15;       // module group (low lanes -> coalesced weights)
        const int b  = tid >> 4;
        const unsigned short* xrow = &xs[b * XSS];
#pragma unroll
        for (int it = 0; it < 4; ++it) {
            const int ml = mg + 16 * it;           // local leaf module
            const int m  = s * 64 + ml;
            const uint2 xp0 = *(const uint2*)&xrow[ml * 8];
            const uint2 xp1 = *(const uint2*)&xrow[ml * 8 + 4];
            const float4 wga = *(const float4*)(Wg + m * 8);
            const float4 wgb = *(const float4*)(Wg + m * 8 + 4);
            const float4 bga = *(const float4*)(bg + m * 8);
            const float4 bgb = *(const float4*)(bg + m * 8 + 4);
            float gene[8];
            gene[0] = fmaf(bflo(xp0.x), wga.x, bga.x);
            gene[1] = fmaf(bfhi(xp0.x), wga.y, bga.y);
            gene[2] = fmaf(bflo(xp0.y), wga.z, bga.z);
            gene[3] = fmaf(bfhi(xp0.y), wga.w, bga.w);
            gene[4] = fmaf(bflo(xp1.x), wgb.x, bgb.x);
            gene[5] = fmaf(bfhi(xp1.x), wgb.y, bgb.y);
            gene[6] = fmaf(bflo(xp1.y), wgb.z, bgb.z);
            gene[7] = fmaf(bfhi(xp1.y), wgb.w, bgb.w);

            float acc[16];
#pragma unroll
            for (int h = 0; h < 16; ++h) acc[h] = 0.f;
            const float* w0m = W0 + m * 128;
#pragma unroll
            for (int g = 0; g < 8; ++g) {
                const float gv = gene[g];
                const float4 wa = *(const float4*)(w0m + g * 16);
                const float4 wb = *(const float4*)(w0m + g * 16 + 4);
                const float4 wc = *(const float4*)(w0m + g * 16 + 8);
                const float4 wd = *(const float4*)(w0m + g * 16 + 12);
                acc[0]  = fmaf(gv, wa.x, acc[0]);   acc[1]  = fmaf(gv, wa.y, acc[1]);
                acc[2]  = fmaf(gv, wa.z, acc[2]);   acc[3]  = fmaf(gv, wa.w, acc[3]);
                acc[4]  = fmaf(gv, wb.x, acc[4]);   acc[5]  = fmaf(gv, wb.y, acc[5]);
                acc[6]  = fmaf(gv, wb.z, acc[6]);   acc[7]  = fmaf(gv, wb.w, acc[7]);
                acc[8]  = fmaf(gv, wc.x, acc[8]);   acc[9]  = fmaf(gv, wc.y, acc[9]);
                acc[10] = fmaf(gv, wc.z, acc[10]);  acc[11] = fmaf(gv, wc.w, acc[11]);
                acc[12] = fmaf(gv, wd.x, acc[12]);  acc[13] = fmaf(gv, wd.y, acc[13]);
                acc[14] = fmaf(gv, wd.z, acc[14]);  acc[15] = fmaf(gv, wd.w, acc[15]);
            }
            unsigned int o[8];
#pragma unroll
            for (int p = 0; p < 8; ++p)
                o[p] = f2bf2(sigf(acc[2 * p]), sigf(acc[2 * p + 1]));
            unsigned short* dst = &h0s[b * H0S + ml * 16];
            *(uint4*)(dst)     = make_uint4(o[0], o[1], o[2], o[3]);
            *(uint4*)(dst + 8) = make_uint4(o[4], o[5], o[6], o[7]);
        }
    }
    __syncthreads();

    // ---------- phase B: h1 MFMA. wave wv -> modules {2wv, 2wv+1} ----------
    {
        const int lane = tid & 63;
        const int wv   = tid >> 6;
        const int n = lane & 15;        // batch row for A, h-col for B/C
        const int q = lane >> 4;
#pragma unroll
        for (int jj = 0; jj < 2; ++jj) {
            const int j = wv * 2 + jj;
            const unsigned short* am  = &h0s[n * H0S + j * 128 + q * 8];
            const unsigned short* w1m = W1t + ((size_t)(s * 8 + j) * 16 + n) * 128 + q * 8;
            floatx4 acc = {0.f, 0.f, 0.f, 0.f};
#pragma unroll
            for (int ks = 0; ks < 4; ++ks) {
                const short8 av = *(const short8*)(am + ks * 32);
                const short8 bv = *(const short8*)(w1m + ks * 32);
                acc = __builtin_amdgcn_mfma_f32_16x16x32_bf16(av, bv, acc, 0, 0, 0);
            }
#pragma unroll
            for (int r = 0; r < 4; ++r)
                h1u[(q * 4 + r) * H1S + j * 16 + n] = f2bf(sigf(acc[r]));
        }
    }
    __syncthreads();

    // ---------- phase C: h2 MFMA (module s), wave 0 only ----------
    if (tid < 64) {
        const int n = tid & 15;
        const int q = tid >> 4;
        const unsigned short* am  = &h1u[n * H1S + q * 8];
        const unsigned short* w2m = W2t + ((size_t)s * 16 + n) * 128 + q * 8;
        floatx4 acc = {0.f, 0.f, 0.f, 0.f};
#pragma unroll
        for (int ks = 0; ks < 4; ++ks) {
            const short8 av = *(const short8*)(am + ks * 32);
            const short8 bv = *(const short8*)(w2m + ks * 32);
            acc = __builtin_amdgcn_mfma_f32_16x16x32_bf16(av, bv, acc, 0, 0, 0);
        }
#pragma unroll
        for (int r = 0; r < 4; ++r)
            h2ws[(size_t)(b0 + q * 4 + r) * 128 + s * 16 + n] = sigf(acc[r]);
    }
}

// ---------- kernel: root (128->16, sigmoid) + final dot(16) ----------
__global__ __launch_bounds__(128) void k_root(
    const float* __restrict__ h2ws, const float* __restrict__ W3,
    const float* __restrict__ Wf, float* __restrict__ out)
{
    __shared__ float w3s[2048];
    __shared__ float wfs[16];
    const int tid = threadIdx.x;
#pragma unroll
    for (int t = 0; t < 16; ++t) w3s[tid + t * 128] = W3[tid + t * 128];
    if (tid < 16) wfs[tid] = Wf[tid];
    __syncthreads();

    const int h = tid & 15;
    const int b = blockIdx.x * 8 + (tid >> 4);
    const float4* hp = (const float4*)(h2ws + (size_t)b * 128);
    float acc = 0.f;
#pragma unroll
    for (int k4 = 0; k4 < 32; ++k4) {
        const float4 hv = hp[k4];
        acc = fmaf(hv.x, w3s[(k4 * 4 + 0) * 16 + h], acc);
        acc = fmaf(hv.y, w3s[(k4 * 4 + 1) * 16 + h], acc);
        acc = fmaf(hv.z, w3s[(k4 * 4 + 2) * 16 + h], acc);
        acc = fmaf(hv.w, w3s[(k4 * 4 + 3) * 16 + h], acc);
    }
    float v = sigf(acc) * wfs[h];
    v += __shfl_down(v, 8, 16);
    v += __shfl_down(v, 4, 16);
    v += __shfl_down(v, 2, 16);
    v += __shfl_down(v, 1, 16);
    if (h == 0) out[b] = v;
}

extern "C" void kernel_launch(void* const* d_in, const int* in_sizes, int n_in,
                              void* d_out, int out_size, void* d_ws, size_t ws_size,
                              hipStream_t stream) {
    const float* x  = (const float*)d_in[0];
    const float* Wg = (const float*)d_in[1];
    const float* bg = (const float*)d_in[2];
    const float* W0 = (const float*)d_in[3];
    const float* W1 = (const float*)d_in[4];
    const float* W2 = (const float*)d_in[5];
    const float* W3 = (const float*)d_in[6];
    const float* Wf = (const float*)d_in[7];
    float* out = (float*)d_out;

    float* h2 = (float*)d_ws;                                   // 4096*128 f32 = 2 MB
    unsigned short* W1t = (unsigned short*)((char*)d_ws + (size_t)2 * 1024 * 1024); // 256 KB
    unsigned short* W2t = W1t + (size_t)64 * 2048;                                  // 32 KB

    k_prep<<<dim3(72), dim3(256), 0, stream>>>(W1, W2, W1t, W2t);
    k_tree<<<dim3((4096 / TB) * 8), dim3(256), 0, stream>>>(x, Wg, bg, W0, W1t, W2t, h2);
    k_root<<<dim3(4096 / 8), dim3(128), 0, stream>>>(h2, W3, Wf, out);
}

// Round 5
// 120.253 us; speedup vs baseline: 1.8737x; 1.8737x over previous
//
#include <hip/hip_runtime.h>
#include <hip/hip_bf16.h>

// RestrictedNN DAG. Round 5: kill phase-A load latency.
//  - phase A remapped to thread=(module, h-quad): W0 loads lane-contiguous
//    (4 lanes = one 64B line), looped over 16 batch rows from LDS.
//  - ALL global loads (x stage, W0/Wg/bg, W1t/W2t fragments) issued at kernel
//    entry into registers; phases B/C touch no global memory.
// B=4096, L0=512 leaves (G=8,H=16), L1=64, L2=8 (FAN=8), root 128->16.

#define TB 16
#define XSS 520      // ushorts per x row (512+8): rows 16B-aligned; 260dw==4 mod 32
#define H0S 1032     // ushorts per h0 row (1024+8): rows 16B-aligned; 516dw==4 mod 32
#define H1S 136      // ushorts per h1 row (128+8): rows 16B-aligned

typedef __attribute__((ext_vector_type(8))) short short8;
typedef __attribute__((ext_vector_type(4))) float floatx4;

__device__ __forceinline__ float sigf(float v) {
    return __builtin_amdgcn_rcpf(1.0f + __expf(-v));
}
__device__ __forceinline__ float bflo(unsigned int p) {
    return __builtin_bit_cast(float, p << 16);
}
__device__ __forceinline__ float bfhi(unsigned int p) {
    return __builtin_bit_cast(float, p & 0xffff0000u);
}
__device__ __forceinline__ unsigned int f2bf_u32(float f) {   // RNE, bf16 in low 16
    unsigned int u = __builtin_bit_cast(unsigned int, f);
    return (u + 0x7fffu + ((u >> 16) & 1u)) >> 16;
}
__device__ __forceinline__ unsigned short f2bf(float f) {
    return (unsigned short)f2bf_u32(f);
}
__device__ __forceinline__ unsigned int f2bf2(float lo, float hi) {
    return f2bf_u32(lo) | (f2bf_u32(hi) << 16);
}

// ---- prep: transpose W1/W2 per module to bf16 [h][k] fragment layout ----
__global__ __launch_bounds__(256) void k_prep(
    const float* __restrict__ W1, const float* __restrict__ W2,
    unsigned short* __restrict__ W1t, unsigned short* __restrict__ W2t)
{
    __shared__ float wl[128 * 17];
    const int mb = blockIdx.x;              // 0..63 -> W1, 64..71 -> W2
    const float* src = (mb < 64) ? (W1 + (size_t)mb * 2048)
                                 : (W2 + (size_t)(mb - 64) * 2048);
    unsigned short* dst = (mb < 64) ? (W1t + (size_t)mb * 2048)
                                    : (W2t + (size_t)(mb - 64) * 2048);
    const int tid = threadIdx.x;
#pragma unroll
    for (int i = 0; i < 8; ++i) {
        const int idx = tid + i * 256;      // [k][h] in, coalesced
        wl[(idx >> 4) * 17 + (idx & 15)] = src[idx];
    }
    __syncthreads();
#pragma unroll
    for (int i = 0; i < 4; ++i) {
        const int u  = tid + i * 256;       // uint index over [h][k] bf16 out
        const int h  = u >> 6;
        const int k  = (u & 63) * 2;
        ((unsigned int*)dst)[u] = f2bf2(wl[k * 17 + h], wl[(k + 1) * 17 + h]);
    }
}

__global__ __launch_bounds__(256) void k_tree(
    const float* __restrict__ x, const float* __restrict__ Wg,
    const float* __restrict__ bg, const float* __restrict__ W0,
    const unsigned short* __restrict__ W1t, const unsigned short* __restrict__ W2t,
    float* __restrict__ h2ws)
{
    __shared__ __align__(16) unsigned short xs[TB * XSS];    // 16640 B (h1 reuses)
    __shared__ __align__(16) unsigned short h0s[TB * H0S];   // 33024 B
    unsigned short* h1u = xs;   // h1 [b][j*16+h] bf16, stride H1S; xs dead after A

    const int tid  = threadIdx.x;
    const int s    = blockIdx.x & 7;
    const int b0   = (blockIdx.x >> 3) * TB;
    const int lane = tid & 63;
    const int wv   = tid >> 6;

    // ---------- issue x stage loads (oldest in pipe), convert as they land ----
    const float* xbase = x + (size_t)b0 * 4096 + s * 512;
    uint2 xp[8];
#pragma unroll
    for (int t = 0; t < 8; ++t) {
        const int i = tid + t * 256;           // over TB*128 float4s
        const int r = i >> 7, c4 = i & 127;
        const float4 v = *(const float4*)(xbase + (size_t)r * 4096 + c4 * 4);
        xp[t] = make_uint2(f2bf2(v.x, v.y), f2bf2(v.z, v.w));
    }

    // ---------- prefetch phase-A weights (lane-contiguous W0) ----------
    const int m_l = tid >> 2;                  // local leaf module 0..63
    const int hq  = tid & 3;                   // h quad
    const int m   = s * 64 + m_l;
    float4 w0r[8];
#pragma unroll
    for (int g = 0; g < 8; ++g)
        w0r[g] = *(const float4*)(W0 + (size_t)m * 128 + g * 16 + hq * 4);
    const float4 wg0 = *(const float4*)(Wg + m * 8);
    const float4 wg1 = *(const float4*)(Wg + m * 8 + 4);
    const float4 bg0 = *(const float4*)(bg + m * 8);
    const float4 bg1 = *(const float4*)(bg + m * 8 + 4);

    // ---------- prefetch phase-B/C MFMA B-fragments ----------
    const int n = lane & 15, q = lane >> 4;
    short8 w1r[2][4];
#pragma unroll
    for (int jj = 0; jj < 2; ++jj) {
        const unsigned short* w1m =
            W1t + ((size_t)(s * 8 + wv * 2 + jj) * 16 + n) * 128 + q * 8;
#pragma unroll
        for (int ks = 0; ks < 4; ++ks)
            w1r[jj][ks] = *(const short8*)(w1m + ks * 32);
    }
    short8 w2r[4];
    if (wv == 0) {
        const unsigned short* w2m = W2t + ((size_t)s * 16 + n) * 128 + q * 8;
#pragma unroll
        for (int ks = 0; ks < 4; ++ks) w2r[ks] = *(const short8*)(w2m + ks * 32);
    }

    // ---------- write x tile to LDS ----------
#pragma unroll
    for (int t = 0; t < 8; ++t) {
        const int i = tid + t * 256;
        const int r = i >> 7, c4 = i & 127;
        *(uint2*)&xs[r * XSS + c4 * 4] = xp[t];
    }
    __syncthreads();

    // ---------- phase A: gene + h0, loop over batch rows ----------
    {
        unsigned short* h0base = &h0s[m_l * 16 + hq * 4];
#pragma unroll 4
        for (int b = 0; b < TB; ++b) {
            const uint4 xv = *(const uint4*)&xs[b * XSS + m_l * 8];
            float gene[8];
            gene[0] = fmaf(bflo(xv.x), wg0.x, bg0.x);
            gene[1] = fmaf(bfhi(xv.x), wg0.y, bg0.y);
            gene[2] = fmaf(bflo(xv.y), wg0.z, bg0.z);
            gene[3] = fmaf(bfhi(xv.y), wg0.w, bg0.w);
            gene[4] = fmaf(bflo(xv.z), wg1.x, bg1.x);
            gene[5] = fmaf(bfhi(xv.z), wg1.y, bg1.y);
            gene[6] = fmaf(bflo(xv.w), wg1.z, bg1.z);
            gene[7] = fmaf(bfhi(xv.w), wg1.w, bg1.w);
            float a0 = 0.f, a1 = 0.f, a2 = 0.f, a3 = 0.f;
#pragma unroll
            for (int g = 0; g < 8; ++g) {
                a0 = fmaf(gene[g], w0r[g].x, a0);
                a1 = fmaf(gene[g], w0r[g].y, a1);
                a2 = fmaf(gene[g], w0r[g].z, a2);
                a3 = fmaf(gene[g], w0r[g].w, a3);
            }
            *(uint2*)(h0base + b * H0S) =
                make_uint2(f2bf2(sigf(a0), sigf(a1)), f2bf2(sigf(a2), sigf(a3)));
        }
    }
    __syncthreads();

    // ---------- phase B: h1 MFMA. wave wv -> modules {2wv, 2wv+1} ----------
    {
#pragma unroll
        for (int jj = 0; jj < 2; ++jj) {
            const int j = wv * 2 + jj;
            const unsigned short* am = &h0s[n * H0S + j * 128 + q * 8];
            floatx4 acc = {0.f, 0.f, 0.f, 0.f};
#pragma unroll
            for (int ks = 0; ks < 4; ++ks) {
                const short8 av = *(const short8*)(am + ks * 32);
                acc = __builtin_amdgcn_mfma_f32_16x16x32_bf16(av, w1r[jj][ks], acc, 0, 0, 0);
            }
#pragma unroll
            for (int r = 0; r < 4; ++r)
                h1u[(q * 4 + r) * H1S + j * 16 + n] = f2bf(sigf(acc[r]));
        }
    }
    __syncthreads();

    // ---------- phase C: h2 MFMA (module s), wave 0 only ----------
    if (wv == 0) {
        const unsigned short* am = &h1u[n * H1S + q * 8];
        floatx4 acc = {0.f, 0.f, 0.f, 0.f};
#pragma unroll
        for (int ks = 0; ks < 4; ++ks) {
            const short8 av = *(const short8*)(am + ks * 32);
            acc = __builtin_amdgcn_mfma_f32_16x16x32_bf16(av, w2r[ks], acc, 0, 0, 0);
        }
#pragma unroll
        for (int r = 0; r < 4; ++r)
            h2ws[(size_t)(b0 + q * 4 + r) * 128 + s * 16 + n] = sigf(acc[r]);
    }
}

// ---------- kernel: root (128->16, sigmoid) + final dot(16) ----------
__global__ __launch_bounds__(128) void k_root(
    const float* __restrict__ h2ws, const float* __restrict__ W3,
    const float* __restrict__ Wf, float* __restrict__ out)
{
    __shared__ float w3s[2048];
    __shared__ float wfs[16];
    const int tid = threadIdx.x;
#pragma unroll
    for (int t = 0; t < 16; ++t) w3s[tid + t * 128] = W3[tid + t * 128];
    if (tid < 16) wfs[tid] = Wf[tid];
    __syncthreads();

    const int h = tid & 15;
    const int b = blockIdx.x * 8 + (tid >> 4);
    const float4* hp = (const float4*)(h2ws + (size_t)b * 128);
    float acc = 0.f;
#pragma unroll
    for (int k4 = 0; k4 < 32; ++k4) {
        const float4 hv = hp[k4];
        acc = fmaf(hv.x, w3s[(k4 * 4 + 0) * 16 + h], acc);
        acc = fmaf(hv.y, w3s[(k4 * 4 + 1) * 16 + h], acc);
        acc = fmaf(hv.z, w3s[(k4 * 4 + 2) * 16 + h], acc);
        acc = fmaf(hv.w, w3s[(k4 * 4 + 3) * 16 + h], acc);
    }
    float v = sigf(acc) * wfs[h];
    v += __shfl_down(v, 8, 16);
    v += __shfl_down(v, 4, 16);
    v += __shfl_down(v, 2, 16);
    v += __shfl_down(v, 1, 16);
    if (h == 0) out[b] = v;
}

extern "C" void kernel_launch(void* const* d_in, const int* in_sizes, int n_in,
                              void* d_out, int out_size, void* d_ws, size_t ws_size,
                              hipStream_t stream) {
    const float* x  = (const float*)d_in[0];
    const float* Wg = (const float*)d_in[1];
    const float* bg = (const float*)d_in[2];
    const float* W0 = (const float*)d_in[3];
    const float* W1 = (const float*)d_in[4];
    const float* W2 = (const float*)d_in[5];
    const float* W3 = (const float*)d_in[6];
    const float* Wf = (const float*)d_in[7];
    float* out = (float*)d_out;

    float* h2 = (float*)d_ws;                                   // 4096*128 f32 = 2 MB
    unsigned short* W1t = (unsigned short*)((char*)d_ws + (size_t)2 * 1024 * 1024); // 256 KB
    unsigned short* W2t = W1t + (size_t)64 * 2048;                                  // 32 KB

    k_prep<<<dim3(72), dim3(256), 0, stream>>>(W1, W2, W1t, W2t);
    k_tree<<<dim3((4096 / TB) * 8), dim3(256), 0, stream>>>(x, Wg, bg, W0, W1t, W2t, h2);
    k_root<<<dim3(4096 / 8), dim3(128), 0, stream>>>(h2, W3, Wf, out);
}